// Round 11
// baseline (184.967 us; speedup 1.0000x reference)
//
#include <hip/hip_runtime.h>

#define HID 128
#define DNODE 64
#define NNODES 50000
#define NEDGES 600000
#define NGRAPHS 64
#define LN_EPS 1e-5f
#define SCAN_BLK 256
#define NSCAN ((NNODES + SCAN_BLK - 1) / SCAN_BLK)   // 196
#define NR 8

#define NZERO (NR * NNODES + NGRAPHS * HID)   // degR + sums = 408192 ints
#define NZERO4 (NZERO / 4)                    // 102048 int4 (exact)
#define Z_BLKS ((NZERO4 + 255) / 256)         // 399
#define PKWC_BLKS (3 * 16384 / 256)           // 192
#define PKWE_BLKS (8192 / 256)                // 32
#define BND_BLKS ((NNODES + 255) / 256)       // 196

#define ENC_BLKS ((NNODES + 63) / 64)         // 782
#define CNT4_BLKS ((NEDGES + 1023) / 1024)    // 586

#define CONV_BLKS ((NNODES + 63) / 64)        // 782
#define FILL_BLKS ((NEDGES + 255) / 256)      // 2344

#define GC_BLKS (NNODES / 16)                 // 3125 (exact)

typedef __attribute__((ext_vector_type(8))) short bf16x8;
typedef __attribute__((ext_vector_type(8))) unsigned short u16x8;
typedef __attribute__((ext_vector_type(4))) float f32x4;

static __device__ __forceinline__ unsigned short f2bf(float f) {
  unsigned int u = __float_as_uint(f);
  u += 0x7fffu + ((u >> 16) & 1u);   // RNE
  return (unsigned short)(u >> 16);
}
static __device__ __forceinline__ float bf2f(unsigned short h) {
  return __uint_as_float(((unsigned int)h) << 16);
}

// ======== prep0: zero degR+sums | pack conv W | pack enc W | graph-bounds ===
__global__ void __launch_bounds__(256) prep0_kernel(
    int4* __restrict__ zp, const float* __restrict__ W,
    unsigned short* __restrict__ Wp, const float* __restrict__ enc_w,
    unsigned short* __restrict__ Wpe, const int* __restrict__ batch,
    int* __restrict__ gstart, int* __restrict__ gend) {
  int b = blockIdx.x;
  if (b < Z_BLKS) {
    int i = b * 256 + threadIdx.x;
    if (i < NZERO4) zp[i] = make_int4(0, 0, 0, 0);
  } else if (b < Z_BLKS + PKWC_BLKS) {
    int t = (b - Z_BLKS) * 256 + threadIdx.x;
    // Wp[layer][((nt*4+kk)*64+lane)*8+i] = W[layer][kk*32+(lane>>4)*8+i][nt*16+(lane&15)]
    int i = t & 7;
    int lane = (t >> 3) & 63;
    int kk = (t >> 9) & 3;
    int nt = (t >> 11) & 7;
    int layer = t >> 14;
    int k = kk * 32 + (lane >> 4) * 8 + i;
    int n = nt * 16 + (lane & 15);
    Wp[t] = f2bf(W[((size_t)layer * HID + k) * HID + n]);
  } else if (b < Z_BLKS + PKWC_BLKS + PKWE_BLKS) {
    int t = (b - Z_BLKS - PKWC_BLKS) * 256 + threadIdx.x;
    // Wpe[((nt*2+kk)*64+lane)*8+i] = enc_w[kk*32+(lane>>4)*8+i][nt*16+(lane&15)]
    int i = t & 7;
    int lane = (t >> 3) & 63;
    int kk = (t >> 9) & 1;
    int nt = (t >> 10) & 7;
    int k = kk * 32 + (lane >> 4) * 8 + i;
    int n = nt * 16 + (lane & 15);
    Wpe[t] = f2bf(enc_w[(size_t)k * HID + n]);
  } else {
    int i = (b - Z_BLKS - PKWC_BLKS - PKWE_BLKS) * 256 + threadIdx.x;
    if (i < NNODES) {
      int g = batch[i];
      if (i == 0 || batch[i - 1] != g) gstart[g] = i;
      if (i == NNODES - 1 || batch[i + 1] != g) gend[g] = i + 1;
    }
  }
}

// ======== prep1: MFMA encoder | replicated edge-count (4 edges/thread) =====
__global__ void __launch_bounds__(256) prep1_kernel(
    const float* __restrict__ x, const unsigned short* __restrict__ Wpe,
    const float* __restrict__ enc_b, const float* __restrict__ ln_g,
    const float* __restrict__ ln_b, unsigned short* __restrict__ Abf,
    const int* __restrict__ dst, int* __restrict__ degR,
    int* __restrict__ erank) {
  __shared__ __align__(16) unsigned short tile[4][16][136];
  int blk = blockIdx.x;
  if (blk >= ENC_BLKS) {
    int b2 = blk - ENC_BLKS;
    int tbase = b2 * 1024 + threadIdx.x * 4;
    if (tbase < NEDGES) {   // NEDGES % 4 == 0, so whole int4 is in range
      int4 d4 = *(const int4*)(dst + tbase);
      int* dr = degR + (b2 & (NR - 1)) * NNODES;
      int4 rk;
      rk.x = atomicAdd(&dr[d4.x], 1);
      rk.y = atomicAdd(&dr[d4.y], 1);
      rk.z = atomicAdd(&dr[d4.z], 1);
      rk.w = atomicAdd(&dr[d4.w], 1);
      *(int4*)(erank + tbase) = rk;
    }
    return;
  }
  int wave = threadIdx.x >> 6;
  int lane = threadIdx.x & 63;
  int l15 = lane & 15, h = lane >> 4;
  int base = blk * 64 + wave * 16;
  int row = base + l15;
  int rowc = row < NNODES ? row : NNODES - 1;
  const float* xr = x + (size_t)rowc * DNODE;
  bf16x8 a[2];
#pragma unroll
  for (int kk = 0; kk < 2; ++kk) {
    float4 p0 = *(const float4*)(xr + kk * 32 + h * 8);
    float4 p1 = *(const float4*)(xr + kk * 32 + h * 8 + 4);
    a[kk][0] = (short)f2bf(p0.x); a[kk][1] = (short)f2bf(p0.y);
    a[kk][2] = (short)f2bf(p0.z); a[kk][3] = (short)f2bf(p0.w);
    a[kk][4] = (short)f2bf(p1.x); a[kk][5] = (short)f2bf(p1.y);
    a[kk][6] = (short)f2bf(p1.z); a[kk][7] = (short)f2bf(p1.w);
  }
  f32x4 acc[8];
#pragma unroll
  for (int nt = 0; nt < 8; ++nt) acc[nt] = (f32x4)(0.f);
  const bf16x8* wp = (const bf16x8*)Wpe;
#pragma unroll
  for (int kk = 0; kk < 2; ++kk)
#pragma unroll
    for (int nt = 0; nt < 8; ++nt)
      acc[nt] = __builtin_amdgcn_mfma_f32_16x16x32_bf16(a[kk], wp[(nt * 2 + kk) * 64 + lane],
                                                        acc[nt], 0, 0, 0);
  float s[4] = {0.f, 0.f, 0.f, 0.f}, s2[4] = {0.f, 0.f, 0.f, 0.f};
#pragma unroll
  for (int nt = 0; nt < 8; ++nt) {
    float bcol = enc_b[nt * 16 + l15];
#pragma unroll
    for (int r = 0; r < 4; ++r) {
      float v = fmaxf(acc[nt][r] + bcol, 0.f);
      acc[nt][r] = v;
      s[r] += v;
      s2[r] = fmaf(v, v, s2[r]);
    }
  }
#pragma unroll
  for (int r = 0; r < 4; ++r) {
#pragma unroll
    for (int o = 1; o < 16; o <<= 1) {
      s[r] += __shfl_xor(s[r], o);
      s2[r] += __shfl_xor(s2[r], o);
    }
  }
  float mu[4], rstd[4];
#pragma unroll
  for (int r = 0; r < 4; ++r) {
    mu[r] = s[r] * (1.0f / HID);
    float var = s2[r] * (1.0f / HID) - mu[r] * mu[r];
    rstd[r] = rsqrtf(var + LN_EPS);
  }
#pragma unroll
  for (int nt = 0; nt < 8; ++nt) {
    float gcol = ln_g[nt * 16 + l15], bbcol = ln_b[nt * 16 + l15];
#pragma unroll
    for (int r = 0; r < 4; ++r)
      tile[wave][h * 4 + r][nt * 16 + l15] =
          f2bf((acc[nt][r] - mu[r]) * rstd[r] * gcol + bbcol);
  }
  __syncthreads();
  int trow = lane >> 2, tseg = lane & 3;
  int orow = base + trow;
  if (orow < NNODES) {
#pragma unroll
    for (int q = 0; q < 4; ++q) {
      u16x8 v = *(const u16x8*)&tile[wave][trow][tseg * 32 + q * 8];
      *(u16x8*)(Abf + (size_t)orow * HID + tseg * 32 + q * 8) = v;
    }
  }
}

// ======== merge replicas + per-block degree sums ========
__global__ void __launch_bounds__(SCAN_BLK) blocksum_kernel(
    const int* __restrict__ degR, int* __restrict__ roff,
    int* __restrict__ degi, int* __restrict__ bsum) {
  int i = blockIdx.x * SCAN_BLK + threadIdx.x;
  int tot = 0;
  if (i < NNODES) {
#pragma unroll
    for (int r = 0; r < NR; ++r) {
      roff[r * NNODES + i] = tot;
      tot += degR[r * NNODES + i];
    }
    degi[i] = tot;
  }
  int v = tot;
#pragma unroll
  for (int off = 32; off; off >>= 1) v += __shfl_down(v, off);
  __shared__ int wsum[4];
  if ((threadIdx.x & 63) == 0) wsum[threadIdx.x >> 6] = v;
  __syncthreads();
  if (threadIdx.x == 0) bsum[blockIdx.x] = wsum[0] + wsum[1] + wsum[2] + wsum[3];
}

// ======== scan: inline scan of bsums + per-element offsets ========
__global__ void __launch_bounds__(SCAN_BLK) offsets_kernel(
    const int* __restrict__ degi, const int* __restrict__ bsum,
    int* __restrict__ off, float* __restrict__ dis) {
  int b = blockIdx.x, t = threadIdx.x;
  __shared__ int sb[SCAN_BLK];
  __shared__ int s[SCAN_BLK];
  __shared__ int wred[4];
  sb[t] = (t < NSCAN) ? bsum[t] : 0;
  __syncthreads();
  int v = (t < b) ? sb[t] : 0;
#pragma unroll
  for (int o = 32; o; o >>= 1) v += __shfl_down(v, o);
  if ((t & 63) == 0) wred[t >> 6] = v;
  __syncthreads();
  int base = wred[0] + wred[1] + wred[2] + wred[3];
  int i = b * SCAN_BLK + t;
  int dv = (i < NNODES) ? degi[i] : 0;
  s[t] = dv;
  __syncthreads();
  for (int d = 1; d < SCAN_BLK; d <<= 1) {
    int x = (t >= d) ? s[t - d] : 0;
    __syncthreads();
    s[t] += x;
    __syncthreads();
  }
  if (i < NNODES) {
    int excl = s[t] - dv + base;
    off[i] = excl;
    dis[i] = rsqrtf((float)dv + 1.0f);
  }
  if (b == 0 && t == 0) off[NNODES] = NEDGES;
}

// ======== fillconv: conv0 via MFMA | atomic-free CSR fill (rank fixup) =====
__global__ void __launch_bounds__(256) fillconv_kernel(
    const unsigned short* __restrict__ Abf, const unsigned short* __restrict__ Wp,
    unsigned short* __restrict__ Bbf, const int* __restrict__ src,
    const int* __restrict__ dst, const int* __restrict__ erank,
    const int* __restrict__ roff, const int* __restrict__ off,
    const float* __restrict__ dis, int2* __restrict__ epack) {
  __shared__ __align__(16) unsigned short tile[4][16][136];
  int blk = blockIdx.x;
  if (blk >= CONV_BLKS) {
    int e = (blk - CONV_BLKS) * 256 + threadIdx.x;
    if (e >= NEDGES) return;
    int d = dst[e];
    int sN = src[e];
    int r = (e >> 10) & (NR - 1);
    int rank = erank[e] + roff[r * NNODES + d];
    int2 v;
    v.x = sN;
    v.y = __float_as_int(dis[sN] * dis[d]);
    epack[off[d] + rank] = v;
    return;
  }
  int wave = threadIdx.x >> 6;
  int lane = threadIdx.x & 63;
  int base = blk * 64 + wave * 16;
  int l15 = lane & 15, hi = lane >> 4;
  int row = base + l15;
  int rowc = row < NNODES ? row : NNODES - 1;
  bf16x8 a[4];
#pragma unroll
  for (int kk = 0; kk < 4; ++kk)
    a[kk] = *(const bf16x8*)(Abf + (size_t)rowc * HID + kk * 32 + hi * 8);
  f32x4 acc[8];
#pragma unroll
  for (int nt = 0; nt < 8; ++nt) acc[nt] = (f32x4)(0.f);
#pragma unroll
  for (int kk = 0; kk < 4; ++kk) {
#pragma unroll
    for (int nt = 0; nt < 8; ++nt) {
      bf16x8 w = *(const bf16x8*)(Wp + (((nt * 4 + kk) * 64 + lane) << 3));
      acc[nt] = __builtin_amdgcn_mfma_f32_16x16x32_bf16(a[kk], w, acc[nt], 0, 0, 0);
    }
  }
#pragma unroll
  for (int nt = 0; nt < 8; ++nt)
#pragma unroll
    for (int r = 0; r < 4; ++r)
      tile[wave][hi * 4 + r][nt * 16 + l15] = f2bf(acc[nt][r]);
  __syncthreads();
  int trow = lane >> 2, tseg = lane & 3;
  int orow = base + trow;
  if (orow < NNODES) {
#pragma unroll
    for (int s = 0; s < 4; ++s) {
      u16x8 v = *(const u16x8*)&tile[wave][trow][tseg * 32 + s * 8];
      *(u16x8*)(Bbf + (size_t)orow * HID + tseg * 32 + s * 8) = v;
    }
  }
}

// ======== gc: gather(layer L) fused with conv(layer L+1) ========
__global__ void __launch_bounds__(1024) gc_kernel(
    const int* __restrict__ off, const int2* __restrict__ epack,
    const float* __restrict__ dis, const float* __restrict__ bias,
    const unsigned short* __restrict__ Bin, const unsigned short* __restrict__ Wnext,
    unsigned short* __restrict__ Bout) {
  __shared__ __align__(16) unsigned short As[16][136];
  __shared__ __align__(16) unsigned short Bs[16][136];
  int w = threadIdx.x >> 6, lane = threadIdx.x & 63;
  int n = blockIdx.x * 16 + w;
  int slot = lane >> 4, p = lane & 15;
  int lo = off[n], hi = off[n + 1];
  float acc0[8], acc1[8];
#pragma unroll
  for (int i = 0; i < 8; ++i) { acc0[i] = 0.f; acc1[i] = 0.f; }
  int idx = lo + slot;
  for (; idx + 4 < hi; idx += 8) {
    int2 e0 = epack[idx];
    int2 e1 = epack[idx + 4];
    float w0 = __int_as_float(e0.y);
    float w1 = __int_as_float(e1.y);
    u16x8 v0 = *(const u16x8*)(Bin + (size_t)e0.x * HID + p * 8);
    u16x8 v1 = *(const u16x8*)(Bin + (size_t)e1.x * HID + p * 8);
#pragma unroll
    for (int i = 0; i < 8; ++i) acc0[i] = fmaf(bf2f(v0[i]), w0, acc0[i]);
#pragma unroll
    for (int i = 0; i < 8; ++i) acc1[i] = fmaf(bf2f(v1[i]), w1, acc1[i]);
  }
  if (idx < hi) {
    int2 e0 = epack[idx];
    float w0 = __int_as_float(e0.y);
    u16x8 v0 = *(const u16x8*)(Bin + (size_t)e0.x * HID + p * 8);
#pragma unroll
    for (int i = 0; i < 8; ++i) acc0[i] = fmaf(bf2f(v0[i]), w0, acc0[i]);
  }
#pragma unroll
  for (int i = 0; i < 8; ++i) {
    float a = acc0[i] + acc1[i];
    a += __shfl_xor(a, 16);
    a += __shfl_xor(a, 32);
    acc0[i] = a;
  }
  if (slot == 0) {
    float dn = dis[n];
    float d2 = dn * dn;
    u16x8 selfv = *(const u16x8*)(Bin + (size_t)n * HID + p * 8);
    float4 b0 = ((const float4*)bias)[p * 2];
    float4 b1 = ((const float4*)bias)[p * 2 + 1];
    float bb[8] = {b0.x, b0.y, b0.z, b0.w, b1.x, b1.y, b1.z, b1.w};
    u16x8 o;
#pragma unroll
    for (int i = 0; i < 8; ++i) {
      float v = fmaxf(fmaf(bf2f(selfv[i]), d2, bb[i]) + acc0[i], 0.f);
      o[i] = f2bf(v);
    }
    *(u16x8*)&As[w][p * 8] = o;   // row w of the block's A-tile
  }
  __syncthreads();
  // conv phase: wave w (<8) computes output cols [16w, 16w+16)
  if (w < 8) {
    bf16x8 a[4];
#pragma unroll
    for (int kk = 0; kk < 4; ++kk)
      a[kk] = *(const bf16x8*)&As[p][kk * 32 + slot * 8];
    f32x4 acc = (f32x4)(0.f);
#pragma unroll
    for (int kk = 0; kk < 4; ++kk) {
      bf16x8 wf = *(const bf16x8*)(Wnext + (((w * 4 + kk) * 64 + lane) << 3));
      acc = __builtin_amdgcn_mfma_f32_16x16x32_bf16(a[kk], wf, acc, 0, 0, 0);
    }
#pragma unroll
    for (int r = 0; r < 4; ++r)
      Bs[slot * 4 + r][w * 16 + p] = f2bf(acc[r]);
  }
  __syncthreads();
  if (threadIdx.x < 256) {
    int row = threadIdx.x >> 4, seg = threadIdx.x & 15;
    *(u16x8*)(Bout + (size_t)(blockIdx.x * 16 + row) * HID + seg * 8) =
        *(const u16x8*)&Bs[row][seg * 8];
  }
}

// ======== g2pool: final gather fused with mean-pool partial sums ========
__global__ void __launch_bounds__(1024) g2pool_kernel(
    const int* __restrict__ off, const int2* __restrict__ epack,
    const float* __restrict__ dis, const float* __restrict__ bias,
    const unsigned short* __restrict__ Bin, const int* __restrict__ batch,
    float* __restrict__ sums) {
  __shared__ float Ps[16][132];
  __shared__ int bg[16];
  int w = threadIdx.x >> 6, lane = threadIdx.x & 63;
  int n = blockIdx.x * 16 + w;
  int slot = lane >> 4, p = lane & 15;
  int lo = off[n], hi = off[n + 1];
  float acc0[8], acc1[8];
#pragma unroll
  for (int i = 0; i < 8; ++i) { acc0[i] = 0.f; acc1[i] = 0.f; }
  int idx = lo + slot;
  for (; idx + 4 < hi; idx += 8) {
    int2 e0 = epack[idx];
    int2 e1 = epack[idx + 4];
    float w0 = __int_as_float(e0.y);
    float w1 = __int_as_float(e1.y);
    u16x8 v0 = *(const u16x8*)(Bin + (size_t)e0.x * HID + p * 8);
    u16x8 v1 = *(const u16x8*)(Bin + (size_t)e1.x * HID + p * 8);
#pragma unroll
    for (int i = 0; i < 8; ++i) acc0[i] = fmaf(bf2f(v0[i]), w0, acc0[i]);
#pragma unroll
    for (int i = 0; i < 8; ++i) acc1[i] = fmaf(bf2f(v1[i]), w1, acc1[i]);
  }
  if (idx < hi) {
    int2 e0 = epack[idx];
    float w0 = __int_as_float(e0.y);
    u16x8 v0 = *(const u16x8*)(Bin + (size_t)e0.x * HID + p * 8);
#pragma unroll
    for (int i = 0; i < 8; ++i) acc0[i] = fmaf(bf2f(v0[i]), w0, acc0[i]);
  }
#pragma unroll
  for (int i = 0; i < 8; ++i) {
    float a = acc0[i] + acc1[i];
    a += __shfl_xor(a, 16);
    a += __shfl_xor(a, 32);
    acc0[i] = a;
  }
  if (slot == 0) {
    float dn = dis[n];
    float d2 = dn * dn;
    u16x8 selfv = *(const u16x8*)(Bin + (size_t)n * HID + p * 8);
    float4 b0 = ((const float4*)bias)[p * 2];
    float4 b1 = ((const float4*)bias)[p * 2 + 1];
    float bb[8] = {b0.x, b0.y, b0.z, b0.w, b1.x, b1.y, b1.z, b1.w};
    float4 o0, o1;
    o0.x = fmaxf(fmaf(bf2f(selfv[0]), d2, bb[0]) + acc0[0], 0.f);
    o0.y = fmaxf(fmaf(bf2f(selfv[1]), d2, bb[1]) + acc0[1], 0.f);
    o0.z = fmaxf(fmaf(bf2f(selfv[2]), d2, bb[2]) + acc0[2], 0.f);
    o0.w = fmaxf(fmaf(bf2f(selfv[3]), d2, bb[3]) + acc0[3], 0.f);
    o1.x = fmaxf(fmaf(bf2f(selfv[4]), d2, bb[4]) + acc0[4], 0.f);
    o1.y = fmaxf(fmaf(bf2f(selfv[5]), d2, bb[5]) + acc0[5], 0.f);
    o1.z = fmaxf(fmaf(bf2f(selfv[6]), d2, bb[6]) + acc0[6], 0.f);
    o1.w = fmaxf(fmaf(bf2f(selfv[7]), d2, bb[7]) + acc0[7], 0.f);
    *(float4*)&Ps[w][p * 8] = o0;
    *(float4*)&Ps[w][p * 8 + 4] = o1;
  }
  if (threadIdx.x < 16) bg[threadIdx.x] = batch[blockIdx.x * 16 + threadIdx.x];
  __syncthreads();
  if (threadIdx.x < HID) {
    int j = threadIdx.x;
    float a = 0.f;
    int cur = bg[0];
    for (int r = 0; r < 16; ++r) {
      int g = bg[r];
      if (g != cur) { atomicAdd(&sums[cur * HID + j], a); a = 0.f; cur = g; }
      a += Ps[r][j];
    }
    atomicAdd(&sums[cur * HID + j], a);
  }
}

// ======== classifier head ========
__global__ void __launch_bounds__(64) cls_kernel(
    const float* __restrict__ sums, const int* __restrict__ gstart,
    const int* __restrict__ gend, const float* __restrict__ c1w,
    const float* __restrict__ c1b, const float* __restrict__ c2w,
    const float* __restrict__ c2b, float* __restrict__ out) {
  int g = blockIdx.x;
  int j = threadIdx.x;
  __shared__ float pooled[HID];
  float cnt = (float)(gend[g] - gstart[g]);
  float inv = 1.0f / fmaxf(cnt, 1.0f);
  pooled[j] = sums[g * HID + j] * inv;
  pooled[j + 64] = sums[g * HID + j + 64] * inv;
  __syncthreads();
  float s = c1b[j];
#pragma unroll 8
  for (int k = 0; k < HID; ++k) s = fmaf(pooled[k], c1w[k * 64 + j], s);
  s = fmaxf(s, 0.f) * c2w[j];
#pragma unroll
  for (int off = 32; off; off >>= 1) s += __shfl_down(s, off);
  if (j == 0) out[g] = s + c2b[0];
}

extern "C" void kernel_launch(void* const* d_in, const int* in_sizes, int n_in,
                              void* d_out, int out_size, void* d_ws, size_t ws_size,
                              hipStream_t stream) {
  const float* x = (const float*)d_in[0];
  const int* edge_index = (const int*)d_in[1];
  const int* batch = (const int*)d_in[3];
  const float* enc_w = (const float*)d_in[4];
  const float* enc_b = (const float*)d_in[5];
  const float* ln_g = (const float*)d_in[6];
  const float* ln_b = (const float*)d_in[7];
  const float* conv_ws = (const float*)d_in[10];
  const float* conv_bs = (const float*)d_in[11];
  const float* c1w = (const float*)d_in[12];
  const float* c1b = (const float*)d_in[13];
  const float* c2w = (const float*)d_in[14];
  const float* c2b = (const float*)d_in[15];
  float* out = (float*)d_out;

  unsigned short* Abf = (unsigned short*)d_ws;        // [NNODES*HID] bf16
  unsigned short* B1 = Abf + (size_t)NNODES * HID;    // [NNODES*HID] bf16
  unsigned short* B2 = B1 + (size_t)NNODES * HID;     // [NNODES*HID] bf16
  unsigned short* Wp = B2 + (size_t)NNODES * HID;     // [3*16384] bf16
  unsigned short* Wpe = Wp + 3 * 16384;               // [8192] bf16
  int2* epack = (int2*)(Wpe + 8192);                  // [NEDGES]
  int* erank = (int*)(epack + NEDGES);                // [NEDGES]
  int* degR = erank + NEDGES;                         // [NR*NNODES]   --+ zeroed
  float* sums = (float*)(degR + NR * NNODES);         // [NGRAPHS*HID] --+ together
  int* roff = (int*)(sums + NGRAPHS * HID);           // [NR*NNODES]
  int* degi = roff + NR * NNODES;                     // [NNODES]
  int* off = degi + NNODES;                           // [NNODES+1]
  float* dis = (float*)(off + NNODES + 1);            // [NNODES]
  int* bsum = (int*)(dis + NNODES);                   // [SCAN_BLK]
  int* gstart = bsum + SCAN_BLK;                      // [NGRAPHS]
  int* gend = gstart + NGRAPHS;                       // [NGRAPHS]

  const int* srcp = edge_index;
  const int* dstp = edge_index + NEDGES;

  prep0_kernel<<<Z_BLKS + PKWC_BLKS + PKWE_BLKS + BND_BLKS, 256, 0, stream>>>(
      (int4*)degR, conv_ws, Wp, enc_w, Wpe, batch, gstart, gend);
  prep1_kernel<<<ENC_BLKS + CNT4_BLKS, 256, 0, stream>>>(
      x, Wpe, enc_b, ln_g, ln_b, Abf, dstp, degR, erank);
  blocksum_kernel<<<NSCAN, SCAN_BLK, 0, stream>>>(degR, roff, degi, bsum);
  offsets_kernel<<<NSCAN, SCAN_BLK, 0, stream>>>(degi, bsum, off, dis);
  fillconv_kernel<<<CONV_BLKS + FILL_BLKS, 256, 0, stream>>>(
      Abf, Wp, B1, srcp, dstp, erank, roff, off, dis, epack);

  // layer0 gather + layer1 conv
  gc_kernel<<<GC_BLKS, 1024, 0, stream>>>(off, epack, dis, conv_bs, B1,
                                          Wp + (size_t)1 * 16384, B2);
  // layer1 gather + layer2 conv
  gc_kernel<<<GC_BLKS, 1024, 0, stream>>>(off, epack, dis, conv_bs + HID, B2,
                                          Wp + (size_t)2 * 16384, B1);
  // layer2 gather + pool
  g2pool_kernel<<<GC_BLKS, 1024, 0, stream>>>(off, epack, dis, conv_bs + 2 * HID,
                                              B1, batch, sums);
  cls_kernel<<<NGRAPHS, 64, 0, stream>>>(sums, gstart, gend, c1w, c1b, c2w, c2b, out);
}